// Round 1
// baseline (1284.799 us; speedup 1.0000x reference)
//
#include <hip/hip_runtime.h>

#define TT 1024
#define BANDS 16
#define CHUNK 128
#define NCHUNK (TT / CHUNK)
#define FINF 1e30f

// Forward DTW: one block per batch, 16 waves (64 rows each), skewed wavefront
// within each wave, 128-col chunks pipelined across waves with one barrier per
// step. Stores 2-bit directions (0=diag,1=up,2=left) packed 16-per-dword in a
// 64x64-tiled layout: dirs dword index = ((b*16+I)*16+J)*256 + (row&63)*4 + ((col>>4)&3)
__global__ __launch_bounds__(1024) void dtw_forward(
    const float* __restrict__ preds,
    const float* __restrict__ targs,
    unsigned* __restrict__ dirs)
{
    __shared__ float2 qsh[TT];
    __shared__ float brow[BANDS + 1][2][CHUNK];   // bottom-row handoff ring

    const int b    = blockIdx.x;
    const int tid  = threadIdx.x;
    const int w    = tid >> 6;
    const int lane = tid & 63;
    const int row  = tid;            // global row in [0,1024)

    {
        const float* tb = targs + (size_t)b * TT * 4;
        float2 q;
        q.x = tb[tid * 4 + 0];
        q.y = tb[tid * 4 + 1];
        qsh[tid] = q;
    }
    if (tid < 2 * CHUNK) {
        brow[0][tid >> 7][tid & (CHUNK - 1)] = FINF;  // band -1 = INF
    }
    const float* pb = preds + (size_t)b * TT * 4;
    const float px = pb[row * 4 + 0];
    const float py = pb[row * 4 + 1];
    __syncthreads();

    float cur = FINF;      // C[row][col-1] (left neighbor), carried across chunks
    float uprev = FINF;    // C[row-1][col-1] (diag neighbor)
    unsigned acc = 0u;     // 16 x 2-bit direction accumulator

    for (int t = 0; t < BANDS + NCHUNK - 1; ++t) {
        const int c = t - w;
        if ((unsigned)c < (unsigned)NCHUNK) {
            const int j0   = c * CHUNK;
            const int slot = c & 1;
            for (int s = 0; s < CHUNK + 63; ++s) {
                const int lc = s - lane;                  // local col (skewed)
                float u_sh = __shfl_up(cur, 1);           // lane-1's C[row-1][col]
                const int bi = (s < CHUNK) ? s : (CHUNK - 1);
                float ub = brow[w][slot][bi];             // prev band bottom row (broadcast)
                float u  = (lane == 0) ? ub : u_sh;       // C[row-1][col]
                const int colm = (j0 + lc) & (TT - 1);
                float2 q = qsh[colm];
                float dx = px - q.x;
                float dy = py - q.y;
                float d  = sqrtf(dx * dx + dy * dy);
                float cd = uprev, cu = u, cl = cur;
                float best = fminf(cd, fminf(cu, cl));
                best = (best > 9e29f) ? 0.0f : best;      // only true at (0,0)
                float val = d + best;
                // argmin([diag, up, left]) with first-min tie-break (matches jnp.argmin)
                unsigned dir = (cd <= cu && cd <= cl) ? 0u : ((cu <= cl) ? 1u : 2u);
                const bool active = ((unsigned)lc < (unsigned)CHUNK);
                if (active) {
                    cur = val;
                    acc = (acc >> 2) | (dir << 30);
                    if ((lc & 15) == 15) {
                        const int colg = j0 + lc;
                        const int I = row >> 6;
                        const int J = colg >> 6;
                        const unsigned idx =
                            ((((unsigned)b * 16u + (unsigned)I) * 16u + (unsigned)J) << 8)
                            | ((unsigned)(row & 63) << 2)
                            | ((unsigned)(colg >> 4) & 3u);
                        dirs[idx] = acc;
                    }
                    if (lane == 63) brow[w + 1][slot][lc] = val;  // handoff to next band
                }
                if (lc < CHUNK) uprev = u;
            }
        }
        __syncthreads();
    }
}

// Backtrace + loss: one wave per batch. Wave-uniform walk; each 64x64 direction
// tile (1 KB) is loaded with one coalesced dwordx4 per lane (lane = tile row);
// per-step direction lookup is a uniform-index __shfl + shift (no global chase).
__global__ __launch_bounds__(64) void dtw_backtrace(
    const float* __restrict__ preds,
    const float* __restrict__ targs,
    const float* __restrict__ subcoef,
    const unsigned* __restrict__ dirs,
    float* __restrict__ out)
{
    __shared__ float2 psh[TT];
    __shared__ float2 qsh[TT];

    const int b    = blockIdx.x;
    const int lane = threadIdx.x;

    const float* pb = preds + (size_t)b * TT * 4;
    const float* tb = targs + (size_t)b * TT * 4;
    for (int k = lane; k < TT; k += 64) {
        psh[k] = make_float2(pb[k * 4 + 0], pb[k * 4 + 1]);
        qsh[k] = make_float2(tb[k * 4 + 0], tb[k * 4 + 1]);
    }
    __syncthreads();

    const float sc0 = subcoef[0];
    const float sc1 = subcoef[1];

    int i = TT - 1, j = TT - 1;
    int tI = -1, tJ = -1;
    uint4 rowdat = make_uint4(0u, 0u, 0u, 0u);
    float loss = 0.0f;

    for (int step = 0; step < 2 * TT; ++step) {
        float2 p = psh[i];
        float2 q = qsh[j];
        loss += fabsf(p.x - q.x) * sc0 + fabsf(p.y - q.y) * sc1;
        if ((i | j) == 0) break;

        const int nI = i >> 6;
        const int nJ = j >> 6;
        if (nI != tI || nJ != tJ) {
            tI = nI; tJ = nJ;
            const uint4* tp = (const uint4*)(dirs +
                ((((unsigned)b * 16u + (unsigned)tI) * 16u + (unsigned)tJ) << 8));
            rowdat = tp[lane];
        }
        const int r   = i & 63;
        const int sel = (j >> 4) & 3;
        unsigned dw = (sel == 0) ? rowdat.x
                    : (sel == 1) ? rowdat.y
                    : (sel == 2) ? rowdat.z
                                 : rowdat.w;
        dw = __shfl(dw, r);
        const unsigned dir = (dw >> ((j & 15) * 2)) & 3u;
        i -= (dir != 2u);   // diag/up move up
        j -= (dir != 1u);   // diag/left move left
    }

    if (lane == 0) atomicAdd(out, loss);
}

extern "C" void kernel_launch(void* const* d_in, const int* in_sizes, int n_in,
                              void* d_out, int out_size, void* d_ws, size_t ws_size,
                              hipStream_t stream)
{
    const float* preds   = (const float*)d_in[0];
    const float* targs   = (const float*)d_in[1];
    const float* subcoef = (const float*)d_in[2];
    float* out = (float*)d_out;
    unsigned* dirs = (unsigned*)d_ws;   // needs B*16*16*1KB = 16 MB for B=64

    const int B = in_sizes[0] / (TT * 4);

    hipMemsetAsync(out, 0, sizeof(float), stream);
    dtw_forward<<<dim3(B), dim3(1024), 0, stream>>>(preds, targs, dirs);
    dtw_backtrace<<<dim3(B), dim3(64), 0, stream>>>(preds, targs, subcoef, dirs, out);
}

// Round 2
// 1150.169 us; speedup vs baseline: 1.1171x; 1.1171x over previous
//
#include <hip/hip_runtime.h>

#define TT 1024
#define BPB 4            // blocks per batch
#define WPB 4            // waves per block (bands of 64 rows)
#define CHUNK 64
#define NCHUNK (TT / CHUNK)
#define FINF 1e30f

// Forward DTW: 4 blocks per batch, each block = 4 waves = 4 row-bands of 64.
// Skewed wavefront within a wave (shfl_up), LDS ring handoff between waves in
// a block, global row buffer + device-scope flags between blocks of the same
// batch. Directions (0=diag,1=up,2=left) packed 16/dword, 64x64-tiled:
// dword idx = ((b*16+I)*16+J)*256 + (row&63)*4 + ((col>>4)&3)
__global__ __launch_bounds__(256) void dtw_forward(
    const float* __restrict__ preds,
    const float* __restrict__ targs,
    unsigned* __restrict__ dirs,
    float* __restrict__ grow,        // [B][3][TT] boundary rows
    unsigned* __restrict__ flags)    // [B][3] chunks-done counters (pre-zeroed)
{
    __shared__ float2 qsh[TT];
    __shared__ float brow[WPB][2][CHUNK];   // handoff ring (wave w reads brow[w])

    const int bid  = blockIdx.x;
    const int b    = bid >> 2;
    const int g    = bid & 3;              // block index within batch
    const int tid  = threadIdx.x;
    const int w    = tid >> 6;
    const int lane = tid & 63;
    const int row  = g * 256 + tid;        // global row in [0,1024)

    {
        const float* tb = targs + (size_t)b * TT * 4;
        for (int k = tid; k < TT; k += 256) {
            float4 tq = ((const float4*)tb)[k];
            qsh[k] = make_float2(tq.x, tq.y);
        }
    }
    const float* pb = preds + (size_t)b * TT * 4;
    float4 pv = ((const float4*)pb)[row];
    const float px = pv.x;
    const float py = pv.y;
    __syncthreads();

    float cur = FINF;      // C[row][col-1], carried across chunks
    float uprev = FINF;    // C[row-1][col-1]
    unsigned acc = 0u;     // 16 x 2-bit direction accumulator

    const unsigned I = (unsigned)(row >> 6);
    unsigned* fprod = (g < 3) ? &flags[b * 3 + g] : nullptr;
    const unsigned* fcons = (g > 0) ? &flags[b * 3 + g - 1] : nullptr;
    float* growp = (g < 3) ? grow + ((size_t)b * 3 + g) * TT : nullptr;
    const float* growc = (g > 0) ? grow + ((size_t)b * 3 + g - 1) * TT : nullptr;

    for (int t = 0; t < WPB + NCHUNK - 1; ++t) {
        const int c = t - w;
        if ((unsigned)c < (unsigned)NCHUNK) {
            const int j0   = c * CHUNK;
            const int slot = c & 1;

            if (w == 0 && g > 0) {
                // wait for upstream block to finish chunk c of its bottom band
                while (__hip_atomic_load(fcons, __ATOMIC_ACQUIRE,
                                         __HIP_MEMORY_SCOPE_AGENT) < (unsigned)(c + 1)) {
                    __builtin_amdgcn_s_sleep(1);
                }
                float v = __hip_atomic_load(growc + j0 + lane, __ATOMIC_RELAXED,
                                            __HIP_MEMORY_SCOPE_AGENT);
                brow[0][slot][lane] = v;
            }

            for (int s = 0; s < CHUNK + 63; ++s) {
                const int lc = s - lane;                  // local col (skewed)
                float u_sh = __shfl_up(cur, 1);           // lane-1's C[row-1][col]
                const int bi = (s < CHUNK) ? s : (CHUNK - 1);
                float ub = brow[w][slot][bi];             // prev band bottom row
                if (w == 0 && g == 0) ub = FINF;
                float u  = (lane == 0) ? ub : u_sh;       // C[row-1][col]
                const int colm = (j0 + lc) & (TT - 1);
                float2 q = qsh[colm];
                float dx = px - q.x;
                float dy = py - q.y;
                float d  = sqrtf(dx * dx + dy * dy);
                float cd = uprev, cu = u, cl = cur;
                float best = fminf(cd, fminf(cu, cl));
                best = (best > 9e29f) ? 0.0f : best;      // only true at (0,0)
                float val = d + best;
                // argmin([diag, up, left]) first-min tie-break (matches jnp.argmin)
                unsigned dir = (cd <= cu && cd <= cl) ? 0u : ((cu <= cl) ? 1u : 2u);
                const bool active = ((unsigned)lc < (unsigned)CHUNK);
                if (active) {
                    cur = val;
                    acc = (acc >> 2) | (dir << 30);
                    if ((lc & 15) == 15) {
                        const int colg = j0 + lc;
                        const unsigned J = (unsigned)(colg >> 6);
                        const unsigned idx =
                            ((((unsigned)b * 16u + I) * 16u + J) << 8)
                            | ((unsigned)(row & 63) << 2)
                            | ((unsigned)(colg >> 4) & 3u);
                        dirs[idx] = acc;
                    }
                    if (lane == 63) {
                        if (w < WPB - 1) brow[w + 1][slot][lc] = val; // LDS handoff
                        else if (g < 3)  growp[j0 + lc] = val;        // global handoff
                    }
                }
                if (lc < CHUNK) uprev = u;
            }

            if (w == WPB - 1 && g < 3) {
                __threadfence();   // drain row stores to device scope
                if (lane == 0)
                    __hip_atomic_store(fprod, (unsigned)(c + 1), __ATOMIC_RELAXED,
                                       __HIP_MEMORY_SCOPE_AGENT);
            }
        }
        __syncthreads();
    }
}

// Backtrace + loss: one wave per batch. Wave-uniform scalar-ish walk; each
// 64x64 tile held in registers (uint4/lane), direction via v_readlane (uniform
// lane index). Path recorded to LDS off the critical chain; loss computed
// lane-parallel afterwards.
__global__ __launch_bounds__(64) void dtw_backtrace(
    const float* __restrict__ preds,
    const float* __restrict__ targs,
    const float* __restrict__ subcoef,
    const unsigned* __restrict__ dirs,
    float* __restrict__ out)
{
    __shared__ float2 psh[TT];
    __shared__ float2 qsh[TT];
    __shared__ unsigned path[2 * TT];

    const int b    = blockIdx.x;
    const int lane = threadIdx.x;

    const float* pb = preds + (size_t)b * TT * 4;
    const float* tb = targs + (size_t)b * TT * 4;
    for (int k = lane; k < TT; k += 64) {
        float4 p4 = ((const float4*)pb)[k];
        float4 t4 = ((const float4*)tb)[k];
        psh[k] = make_float2(p4.x, p4.y);
        qsh[k] = make_float2(t4.x, t4.y);
    }
    __syncthreads();

    int i = TT - 1, j = TT - 1;
    int tI = -1, tJ = -1;
    uint4 rowdat = make_uint4(0u, 0u, 0u, 0u);
    int n = 0;

    for (;;) {
        if (lane == 0) path[n] = ((unsigned)i << 16) | (unsigned)j;
        ++n;
        if ((i | j) == 0) break;

        const int nI = i >> 6;
        const int nJ = j >> 6;
        if (nI != tI || nJ != tJ) {
            tI = nI; tJ = nJ;
            const uint4* tp = (const uint4*)(dirs +
                ((((unsigned)b * 16u + (unsigned)tI) * 16u + (unsigned)tJ) << 8));
            rowdat = tp[lane];
        }
        const int r   = i & 63;
        const int sel = (j >> 4) & 3;
        unsigned dwa = (sel & 1) ? rowdat.y : rowdat.x;
        unsigned dwb = (sel & 1) ? rowdat.w : rowdat.z;
        unsigned dwv = (sel & 2) ? dwb : dwa;
        unsigned dw  = (unsigned)__builtin_amdgcn_readlane((int)dwv,
                            __builtin_amdgcn_readfirstlane(r));
        const unsigned dir = (dw >> ((j & 15) * 2)) & 3u;
        i -= (dir != 2u);   // diag/up move up
        j -= (dir != 1u);   // diag/left move left
    }
    __syncthreads();

    const float sc0 = subcoef[0];
    const float sc1 = subcoef[1];
    float loss = 0.0f;
    for (int k = lane; k < n; k += 64) {
        unsigned pk = path[k];
        int pi = (int)(pk >> 16);
        int pj = (int)(pk & 0xffffu);
        float2 p = psh[pi];
        float2 q = qsh[pj];
        loss += fabsf(p.x - q.x) * sc0 + fabsf(p.y - q.y) * sc1;
    }
    for (int off = 32; off; off >>= 1) loss += __shfl_down(loss, off);
    if (lane == 0) atomicAdd(out, loss);
}

extern "C" void kernel_launch(void* const* d_in, const int* in_sizes, int n_in,
                              void* d_out, int out_size, void* d_ws, size_t ws_size,
                              hipStream_t stream)
{
    const float* preds   = (const float*)d_in[0];
    const float* targs   = (const float*)d_in[1];
    const float* subcoef = (const float*)d_in[2];
    float* out = (float*)d_out;

    const int B = in_sizes[0] / (TT * 4);

    // workspace layout
    const size_t dirsBytes = (size_t)B * 16 * 16 * 256 * 4;   // 16 MB @ B=64
    unsigned* dirs = (unsigned*)d_ws;
    float* grow    = (float*)((char*)d_ws + dirsBytes);       // B*3*TT floats
    unsigned* flags = (unsigned*)((char*)d_ws + dirsBytes + (size_t)B * 3 * TT * 4);

    hipMemsetAsync(flags, 0, (size_t)B * 3 * 4, stream);
    hipMemsetAsync(out, 0, sizeof(float), stream);
    dtw_forward<<<dim3(B * BPB), dim3(256), 0, stream>>>(preds, targs, dirs, grow, flags);
    dtw_backtrace<<<dim3(B), dim3(64), 0, stream>>>(preds, targs, subcoef, dirs, out);
}

// Round 5
// 796.087 us; speedup vs baseline: 1.6139x; 1.4448x over previous
//
#include <hip/hip_runtime.h>

#define TT   1024
#define NW   34          // 32-col windows per lane (covers 63-lane skew: (1023+63)>>5 = 33)
#define FINF 1e30f

// dirs layout: uint2 {ne2_mask, diag_mask} per (batch, band, window t, lane):
//   index = ((b*16 + bi) * NW + t) * 64 + lane
// window t of lane L covers cols [32t - L, 32t - L + 31]; bit k = col 32t - L + k.
// ne2 bit: dir != left (i decreases). diag bit: dir == diag (first-min argmin).

template <bool SRCG>
__device__ __forceinline__ float load_src(const float* g, const float* l, int c) {
    if (SRCG) return __hip_atomic_load(g + c, __ATOMIC_RELAXED, __HIP_MEMORY_SCOPE_AGENT);
    else      return __hip_atomic_load(l + c, __ATOMIC_RELAXED, __HIP_MEMORY_SCOPE_WORKGROUP);
}

// One wave = one 64-row band. Continuous skew: lane L handles col s-L at iter s.
// Cross-lane dependency via __shfl_up (rounds 1-2 proven).
// IMPORTANT: cur starts FINF for ALL lanes (incl. (0,0)); the origin cell is
// handled by the per-cell best>9e29 clamp, exactly as round 2. A cur=0 init
// trick is WRONG: lane 1 shfl-reads lane 0's init value at s=0 and poisons its
// uprev (C[0][-1] must be INF) — that was the rounds-3/4 bug.
// Boundary row in/out via sign-bit-valid mailboxes (values >= 0 are valid;
// 0xAA poison / -1.0f init are negative).
template <bool HASSRC, bool SRCG, bool DSTG>
__device__ void run_band(
    int b, int bi, int lane,
    const float2* __restrict__ qsh,
    const float* src_g, const float* src_l,
    float* dst_g, float* dst_l,
    uint2* __restrict__ dirs,
    const float* __restrict__ preds)
{
    const int row = bi * 64 + lane;
    float4 pv = ((const float4*)preds)[(size_t)b * TT + row];
    const float px = pv.x, py = pv.y;
    const bool is63 = (lane == 63);

    float cur   = FINF;    // C[row][col-1], FINF everywhere (see note above)
    float uprev = FINF;    // C[row-1][col-1]
    unsigned accd = 0u, accu = 0u;

    float bnd_cur[32];
    float bnd_nxt[32];
    if (HASSRC) {
#pragma unroll
        for (int k = 0; k < 32; ++k) bnd_cur[k] = load_src<SRCG>(src_g, src_l, k);
    }

    const size_t dbase = (size_t)(b * 16 + bi) * NW * 64;

    for (int T = 0; T < NW; ++T) {
        // prefetch next body's boundary values (32 cols ahead)
        if (HASSRC && T < NW - 1) {
#pragma unroll
            for (int k = 0; k < 32; ++k) {
                int c = T * 32 + 32 + k; c = c < TT ? c : TT - 1;
                bnd_nxt[k] = load_src<SRCG>(src_g, src_l, c);
            }
        }
#pragma unroll
        for (int sub = 0; sub < 4; ++sub) {
            if (HASSRC) {
                // validate this 8-col group (sign-bit test); spin-reload if stale
                for (;;) {
                    unsigned sg = 0u;
#pragma unroll
                    for (int k2 = 0; k2 < 8; ++k2) sg |= __float_as_uint(bnd_cur[sub * 8 + k2]);
                    if (!(sg & 0x80000000u)) break;
                    __builtin_amdgcn_s_sleep(2);
#pragma unroll
                    for (int k2 = 0; k2 < 8; ++k2) {
                        int c = T * 32 + sub * 8 + k2; c = c < TT ? c : TT - 1;
                        bnd_cur[sub * 8 + k2] = load_src<SRCG>(src_g, src_l, c);
                    }
                }
            }
#pragma unroll
            for (int k2 = 0; k2 < 8; ++k2) {
                const int k = sub * 8 + k2;
                const int s = T * 32 + k;
                const int col = s - lane;
                float2 q = qsh[col & (TT - 1)];
                float dx = px - q.x, dy = py - q.y;
                float d = sqrtf(dx * dx + dy * dy);      // same expr as rounds 1-2 (absmax 0)

                float bnd = HASSRC ? bnd_cur[k] : FINF;
                float u_sh = __shfl_up(cur, 1);          // lane L-1's C[r-1][col]
                float u = (lane == 0) ? bnd : u_sh;      // lane 0: boundary row
                float m2   = fminf(u, cur);              // min(cu, cl)
                float best = fminf(uprev, m2);           // min(cd, .)
                best = (best > 9e29f) ? 0.0f : best;     // only true at (0,0) — round-2 proven
                float val  = d + best;

                unsigned bd = (uprev <= m2) ? 1u : 0u;           // diag (first-min)
                unsigned bu = ((u <= cur) ? 1u : 0u) | bd;       // dir != left
                accd = (accd << 1) | bd;
                accu = (accu << 1) | bu;

                bool act = (lane <= s);                  // col >= 0
                cur = act ? val : cur;
                uprev = u;

                // publish bottom row (band handoff)
                if (is63 && (unsigned)(s - 63) < 1024u) {
                    if (DSTG) __hip_atomic_store(dst_g + (s - 63), cur, __ATOMIC_RELAXED, __HIP_MEMORY_SCOPE_AGENT);
                    else      __hip_atomic_store(dst_l + (s - 63), cur, __ATOMIC_RELAXED, __HIP_MEMORY_SCOPE_WORKGROUP);
                }
            }
        }
        // flush masks: bitreverse so bit k = col 32T - lane + k
        dirs[dbase + (size_t)T * 64 + lane] =
            make_uint2(__builtin_bitreverse32(accu), __builtin_bitreverse32(accd));
        accd = accu = 0u;
        if (HASSRC && T < NW - 1) {
#pragma unroll
            for (int k = 0; k < 32; ++k) bnd_cur[k] = bnd_nxt[k];
        }
    }
}

__global__ __launch_bounds__(256) void dtw_forward(
    const float* __restrict__ preds,
    const float* __restrict__ targs,
    uint2* __restrict__ dirs,
    float* __restrict__ brow_g)     // [B][4][TT]; slot 3 = sink
{
    __shared__ float2 qsh[TT];
    __shared__ float brow_lds[3][TT];

    const int tid  = threadIdx.x;
    const int w    = tid >> 6;
    const int lane = tid & 63;
    const int b    = blockIdx.x >> 2;
    const int g    = blockIdx.x & 3;
    const int bi   = g * 4 + w;

    for (int k = tid; k < TT; k += 256) {
        float4 t4 = ((const float4*)targs)[(size_t)b * TT + k];
        qsh[k] = make_float2(t4.x, t4.y);
    }
    for (int k = tid; k < 3 * TT; k += 256) ((float*)brow_lds)[k] = -1.0f;  // invalid
    __syncthreads();

    const float* srcg = brow_g + ((size_t)b * 4 + (g - 1)) * TT;   // valid only when g>0
    float*       dstg = brow_g + ((size_t)b * 4 + g) * TT;         // g==3 -> sink slot
    const float* srcl = (w > 0) ? brow_lds[w - 1] : nullptr;
    float*       dstl = (w < 3) ? brow_lds[w] : nullptr;

    if (w == 0) {
        if (g == 0) run_band<false, false, false>(b, bi, lane, qsh, nullptr, nullptr, nullptr, dstl, dirs, preds);
        else        run_band<true,  true,  false>(b, bi, lane, qsh, srcg,    nullptr, nullptr, dstl, dirs, preds);
    } else if (w < 3) {
        run_band<true, false, false>(b, bi, lane, qsh, nullptr, srcl, nullptr, dstl, dirs, preds);
    } else {
        run_band<true, false, true >(b, bi, lane, qsh, nullptr, srcl, dstg,   nullptr, dirs, preds);
    }
}

// Backtrace: one wave per batch. ~1 serial step per ROW: funnel-shift the
// per-lane mask windows, readlane the current row's 32-col view, clz finds the
// whole left-run. Intervals recorded to LDS; loss summed lane-parallel after.
__global__ __launch_bounds__(64) void dtw_backtrace(
    const float* __restrict__ preds,
    const float* __restrict__ targs,
    const float* __restrict__ subcoef,
    const uint2* __restrict__ dirs,
    float* __restrict__ out)
{
    __shared__ float2 qsh[TT];
    __shared__ float2 psh[TT];
    __shared__ uint2 msk[2][NW * 64];
    __shared__ unsigned recs[2048];

    const int b = blockIdx.x, lane = threadIdx.x;

    for (int k = lane; k < TT; k += 64) {
        float4 t4 = ((const float4*)targs)[(size_t)b * TT + k];
        float4 p4 = ((const float4*)preds)[(size_t)b * TT + k];
        qsh[k] = make_float2(t4.x, t4.y);
        psh[k] = make_float2(p4.x, p4.y);
    }
    const uint2* dir_b = dirs + (size_t)b * 16 * (NW * 64);
    {
        const uint2* s15 = dir_b + (size_t)15 * (NW * 64);
#pragma unroll
        for (int t = 0; t < NW; ++t) msk[1][t * 64 + lane] = s15[t * 64 + lane];
    }
    uint2 pref[NW];
    {
        const uint2* s14 = dir_b + (size_t)14 * (NW * 64);
#pragma unroll
        for (int t = 0; t < NW; ++t) pref[t] = s14[t * 64 + lane];
    }
    __syncthreads();

    const float sc0 = subcoef[0];
    const float sc1 = subcoef[1];

    int j = TT - 1;
    int n = 0;
    bool done = false;

    for (int bi = 15; bi >= 0 && !done; --bi) {
        const uint2* M = msk[bi & 1];
        int t0 = (j + lane) >> 5;
        uint2 W0 = M[t0 * 64 + lane];
        uint2 W1 = M[max(t0 - 1, 0) * 64 + lane];
        uint2 W2 = M[max(t0 - 2, 0) * 64 + lane];
        uint2 Wp = M[max(t0 - 3, 0) * 64 + lane];

        for (int rr = 63; rr >= 0; --rr) {
            int r = bi * 64 + rr;
            if (r == 0) {
                if (lane == 0) recs[n] = ((unsigned)j << 10);   // row 0: cols j..0
                ++n; done = true; break;
            }
            for (;;) {
                unsigned sh = ((unsigned)(j + lane) & 31u) + 1u;
                unsigned long long pn = (((unsigned long long)W0.x) << 32) | W1.x;
                unsigned rn = (unsigned)(pn >> sh);                    // bit31 = col j
                unsigned vn = (unsigned)__builtin_amdgcn_readlane((int)rn, rr);
                if (vn == 0u) {
                    // 32 consecutive lefts: record, jump a whole window
                    if (lane == 0) recs[n] = ((unsigned)r << 20) | ((unsigned)j << 10) | (unsigned)(j - 31);
                    ++n;
                    j -= 32;
                    W0 = W1; W1 = W2; W2 = Wp;
                    int tp = ((j + lane) >> 5) - 3;
                    Wp = M[max(tp, 0) * 64 + lane];
                    continue;
                }
                unsigned long long pd = (((unsigned long long)W0.y) << 32) | W1.y;
                unsigned rd = (unsigned)(pd >> sh);
                int clz = __builtin_clz(vn);
                int j2 = j - clz;
                unsigned vd = (unsigned)__builtin_amdgcn_readlane((int)rd, rr);
                int diag = (int)((vd >> (31 - clz)) & 1u);
                if (lane == 0) recs[n] = ((unsigned)r << 20) | ((unsigned)j << 10) | (unsigned)j2;
                ++n;
                int jn = j2 - diag;

                int nt0 = (jn + lane) >> 5;
                int t0c = (j + lane) >> 5;
                if (__ballot(t0c - nt0 >= 2) != 0ull) {
                    W0 = M[nt0 * 64 + lane];
                    W1 = M[max(nt0 - 1, 0) * 64 + lane];
                    W2 = M[max(nt0 - 2, 0) * 64 + lane];
                    Wp = M[max(nt0 - 3, 0) * 64 + lane];
                } else {
                    bool d1 = (nt0 < t0c);
                    uint2 wnew = M[max(nt0 - 3, 0) * 64 + lane];
                    W0 = d1 ? W1 : W0;
                    W1 = d1 ? W2 : W1;
                    W2 = d1 ? Wp : W2;
                    Wp = d1 ? wnew : Wp;
                }
                j = jn;
                break;
            }
        }
        if (done) break;
        if (bi > 0) {
            uint2* Mn = msk[(bi - 1) & 1];
#pragma unroll
            for (int t = 0; t < NW; ++t) Mn[t * 64 + lane] = pref[t];
            if (bi > 1) {
                const uint2* s2 = dir_b + (size_t)(bi - 2) * (NW * 64);
#pragma unroll
                for (int t = 0; t < NW; ++t) pref[t] = s2[t * 64 + lane];
            }
        }
    }
    __syncthreads();

    float acc = 0.0f;
    for (int k = lane; k < n; k += 64) {
        unsigned rec = recs[k];
        int r  = (int)(rec >> 20);
        int jh = (int)((rec >> 10) & 1023u);
        int jl = (int)(rec & 1023u);
        float2 p = psh[r];
        for (int c = jl; c <= jh; ++c) {
            float2 q = qsh[c];
            acc += fabsf(p.x - q.x) * sc0 + fabsf(p.y - q.y) * sc1;
        }
    }
    for (int o = 32; o; o >>= 1) acc += __shfl_down(acc, o);
    if (lane == 0) atomicAdd(out, acc);
}

extern "C" void kernel_launch(void* const* d_in, const int* in_sizes, int n_in,
                              void* d_out, int out_size, void* d_ws, size_t ws_size,
                              hipStream_t stream)
{
    const float* preds   = (const float*)d_in[0];
    const float* targs   = (const float*)d_in[1];
    const float* subcoef = (const float*)d_in[2];
    float* out = (float*)d_out;

    const int B = in_sizes[0] / (TT * 4);

    const size_t dirsBytes = (size_t)B * 16 * NW * 64 * sizeof(uint2);   // ~17.8 MB @ B=64
    uint2* dirs  = (uint2*)d_ws;
    float* browg = (float*)((char*)d_ws + dirsBytes);                    // [B][4][TT]

    hipMemsetAsync(out, 0, sizeof(float), stream);
    dtw_forward<<<dim3(B * 4), dim3(256), 0, stream>>>(preds, targs, dirs, browg);
    dtw_backtrace<<<dim3(B), dim3(64), 0, stream>>>(preds, targs, subcoef, dirs, out);
}

// Round 6
// 768.241 us; speedup vs baseline: 1.6724x; 1.0362x over previous
//
#include <hip/hip_runtime.h>

#define TT   1024
#define NW   34          // 32-iter windows (lane 63 reaches iter 1086)
#define FINF 1e30f

// dirs layout (identical bit format to round 5, keyed by 64-row band):
//   uint2 {ne2_mask, diag_mask} at index ((b*16+bi)*NW + T)*64 + rr
//   where rr = row within band, and stored bit k of window T = col 32T - o + k
//   with o = the skew-lane that computed the row: o = (bi&3)*16 + (rr>>2).
// ne2 bit: dir != left. diag bit: dir == diag (first-min argmin).

// ---------------- K1: forward DP, 1 block (4 waves) per batch ----------------
// Wave w owns rows 256w..256w+255; lane L owns 4 rows 256w+4L..+3.
// Continuous skew: at iter s, lane L computes col s-L for its 4 rows (chain =
// 1 shfl + 4 dependent cells). Wave-to-wave boundary rows via LDS mailboxes
// with sign-bit validity (costs >= 0; -1.0f init / 0xAA poison are negative),
// validated just-in-time in 8-col groups (producer's natural lead is ~70).
__global__ __launch_bounds__(256) void dtw_forward(
    const float* __restrict__ preds,
    const float* __restrict__ targs,
    uint2* __restrict__ dirs)
{
    __shared__ float2 qsh[TT];
    __shared__ float mbox[3][TT];

    const int tid  = threadIdx.x;
    const int w    = tid >> 6;
    const int lane = tid & 63;
    const int b    = blockIdx.x;

    for (int k = tid; k < TT; k += 256) {
        float4 t4 = ((const float4*)targs)[(size_t)b * TT + k];
        qsh[k] = make_float2(t4.x, t4.y);
    }
    for (int k = tid; k < 3 * TT; k += 256) ((float*)mbox)[k] = -1.0f;

    float px[4], py[4];
#pragma unroll
    for (int k = 0; k < 4; ++k) {
        const int row = w * 256 + lane * 4 + k;
        float4 pv = ((const float4*)preds)[(size_t)b * TT + row];
        px[k] = pv.x; py[k] = pv.y;
    }
    __syncthreads();

    const float* src = (w > 0) ? mbox[w - 1] : nullptr;
    float*       dst = (w < 3) ? mbox[w]     : nullptr;

    // cur starts FINF for ALL lanes; (0,0) handled by the best>9e29 clamp
    // (round-2 proven). Any other init leaks through the shfl chain (r3/r4 bug).
    float cur0 = FINF, cur1 = FINF, cur2 = FINF, cur3 = FINF;
    float uprev0 = FINF;
    unsigned au[4] = {0,0,0,0}, ad[4] = {0,0,0,0};
    float bnd[8];
#pragma unroll
    for (int k = 0; k < 8; ++k) bnd[k] = FINF;

    const int bb = b * 16 + 4 * w + (lane >> 4);   // 64-row band index
    const int r0 = (lane & 15) * 4;                // row within band
    const bool is63 = (lane == 63);

    float shp = __shfl_up(cur3, 1);   // pipelined up-neighbor (FINF initially)

    for (int T = 0; T < NW; ++T) {
#pragma unroll 1
        for (int sub = 0; sub < 4; ++sub) {
            const int s0 = T * 32 + sub * 8;
            if (w > 0 && s0 < TT) {
                // JIT validate boundary cols [s0, s0+7] (sign-bit test)
                for (;;) {
                    unsigned sg = 0u;
#pragma unroll
                    for (int k2 = 0; k2 < 8; ++k2) {
                        bnd[k2] = __hip_atomic_load(src + s0 + k2, __ATOMIC_RELAXED,
                                                    __HIP_MEMORY_SCOPE_WORKGROUP);
                        sg |= __float_as_uint(bnd[k2]);
                    }
                    if (!(sg & 0x80000000u)) break;
                    __builtin_amdgcn_s_sleep(1);
                }
            }
#pragma unroll
            for (int k2 = 0; k2 < 8; ++k2) {
                const int s   = s0 + k2;
                const int col = s - lane;
                float2 q = qsh[col & (TT - 1)];
                float dx0 = px[0] - q.x, dy0 = py[0] - q.y;
                float dx1 = px[1] - q.x, dy1 = py[1] - q.y;
                float dx2 = px[2] - q.x, dy2 = py[2] - q.y;
                float dx3 = px[3] - q.x, dy3 = py[3] - q.y;
                float d0 = sqrtf(dx0 * dx0 + dy0 * dy0);
                float d1 = sqrtf(dx1 * dx1 + dy1 * dy1);
                float d2 = sqrtf(dx2 * dx2 + dy2 * dy2);
                float d3 = sqrtf(dx3 * dx3 + dy3 * dy3);

                float u0 = (lane == 0) ? ((w == 0) ? FINF : bnd[k2]) : shp;
                const bool act = (lane <= s);

                float c0o = cur0, c1o = cur1, c2o = cur2, c3o = cur3;

                // row k=0: cd=uprev0, cu=u0, cl=c0o (clamp: only (0,0) has all-INF)
                float m2a = fminf(u0, c0o);
                float ba  = fminf(uprev0, m2a);
                ba = (ba > 9e29f) ? 0.0f : ba;
                float v0 = d0 + ba;
                unsigned bd0 = (uprev0 <= m2a) ? 1u : 0u;
                unsigned bu0 = ((u0 <= c0o) ? 1u : 0u) | bd0;
                // row k=1: cd=c0o, cu=v0, cl=c1o
                float m2b = fminf(v0, c1o);
                float v1 = d1 + fminf(c0o, m2b);
                unsigned bd1 = (c0o <= m2b) ? 1u : 0u;
                unsigned bu1 = ((v0 <= c1o) ? 1u : 0u) | bd1;
                // row k=2
                float m2c = fminf(v1, c2o);
                float v2 = d2 + fminf(c1o, m2c);
                unsigned bd2 = (c1o <= m2c) ? 1u : 0u;
                unsigned bu2 = ((v1 <= c2o) ? 1u : 0u) | bd2;
                // row k=3
                float m2d = fminf(v2, c3o);
                float v3 = d3 + fminf(c2o, m2d);
                unsigned bd3 = (c2o <= m2d) ? 1u : 0u;
                unsigned bu3 = ((v2 <= c3o) ? 1u : 0u) | bd3;

                au[0] = (au[0] << 1) | bu0;  ad[0] = (ad[0] << 1) | bd0;
                au[1] = (au[1] << 1) | bu1;  ad[1] = (ad[1] << 1) | bd1;
                au[2] = (au[2] << 1) | bu2;  ad[2] = (ad[2] << 1) | bd2;
                au[3] = (au[3] << 1) | bu3;  ad[3] = (ad[3] << 1) | bd3;

                cur0 = act ? v0 : c0o;
                cur1 = act ? v1 : c1o;
                cur2 = act ? v2 : c2o;
                cur3 = act ? v3 : c3o;
                uprev0 = u0;

                if (is63 && w < 3 && (unsigned)(s - 63) < 1024u)
                    __hip_atomic_store(dst + (s - 63), cur3, __ATOMIC_RELAXED,
                                       __HIP_MEMORY_SCOPE_WORKGROUP);

                shp = __shfl_up(cur3, 1);   // for next iter (col s+1-L)
            }
        }
#pragma unroll
        for (int k = 0; k < 4; ++k) {
            dirs[(size_t)(bb * NW + T) * 64 + r0 + k] =
                make_uint2(__builtin_bitreverse32(au[k]), __builtin_bitreverse32(ad[k]));
            au[k] = 0u; ad[k] = 0u;
        }
    }
}

// ---------------- K2: parallel per-band walk ----------------
// Block = (batch, band). For every possible entry column j (1024 threads, one
// each), walk the 64 rows of the band: segment loss + exit column. Fully
// parallel — the serial global backtrace collapses to 16 lookups (K3).
__global__ __launch_bounds__(1024) void dtw_bandwalk(
    const float* __restrict__ preds,
    const float* __restrict__ targs,
    const float* __restrict__ subcoef,
    const uint2* __restrict__ dirs,
    float* __restrict__ seg,
    unsigned short* __restrict__ exitc)
{
    __shared__ uint2 raw[NW * 64];
    __shared__ unsigned nebit[64][32];
    __shared__ unsigned dgbit[64][32];
    __shared__ float2 qsh[TT];
    __shared__ float2 psh[64];

    const int tid = threadIdx.x;
    const int b   = blockIdx.x >> 4;
    const int bi  = blockIdx.x & 15;

    for (int i = tid; i < NW * 64; i += 1024)
        raw[i] = dirs[(size_t)(b * 16 + bi) * (NW * 64) + i];
    {
        float4 t4 = ((const float4*)targs)[(size_t)b * TT + tid];
        qsh[tid] = make_float2(t4.x, t4.y);
    }
    if (tid < 64) {
        float4 p4 = ((const float4*)preds)[(size_t)b * TT + bi * 64 + tid];
        psh[tid] = make_float2(p4.x, p4.y);
    }
    __syncthreads();

    // realign skewed windows to row-major 32-col dwords:
    // aligned bit n of dword u = col 32u+n = source window T0=u+(o>>5) bit n+(o&31)
    for (int i = tid; i < 64 * 32; i += 1024) {
        const int rr = i >> 5, u = i & 31;
        const int o  = ((bi & 3) << 4) + (rr >> 2);
        const int T0 = u + (o >> 5);
        const int sh = o & 31;
        uint2 A = raw[T0 * 64 + rr];
        uint2 Bv = raw[(T0 + 1) * 64 + rr];
        nebit[rr][u] = sh ? ((A.x >> sh) | (Bv.x << (32 - sh))) : A.x;
        dgbit[rr][u] = sh ? ((A.y >> sh) | (Bv.y << (32 - sh))) : A.y;
    }
    __syncthreads();

    const float sc0 = subcoef[0], sc1 = subcoef[1];
    int j = tid;            // entry column
    float loss = 0.0f;

    for (int rr = 63; rr >= 0; --rr) {
        float2 p = psh[rr];
        for (;;) {
            const int u = j >> 5, m = j & 31;
            unsigned wne = nebit[rr][u] << (31 - m);   // bit31 = col j
            if (wne == 0u) {
                // whole remainder of this dword is left-moves
                for (int c = j; c >= (u << 5); --c) {
                    float2 q = qsh[c];
                    loss += fabsf(p.x - q.x) * sc0 + fabsf(p.y - q.y) * sc1;
                }
                j = (u << 5) - 1;    // col-0 ne bit is always 1 -> u>0 here
                continue;
            }
            const int cz = __builtin_clz(wne);         // # of left-moves
            const int j2 = j - cz;
            for (int c = j; c >= j2; --c) {
                float2 q = qsh[c];
                loss += fabsf(p.x - q.x) * sc0 + fabsf(p.y - q.y) * sc1;
            }
            if (rr > 0 || bi > 0) {
                const int diag = (int)((dgbit[rr][j2 >> 5] >> (j2 & 31)) & 1u);
                j = j2 - diag;       // diag bit at col 0 is 0 (except (0,0)) -> j>=0
            } else {
                j = 0;               // global row 0: run ended at col 0, done
            }
            break;
        }
    }
    const size_t oidx = ((size_t)(b * 16 + bi) << 10) + tid;
    seg[oidx] = loss;
    exitc[oidx] = (unsigned short)j;
}

// ---------------- K3: stitch ----------------
__global__ void dtw_stitch(const float* __restrict__ seg,
                           const unsigned short* __restrict__ exitc,
                           float* __restrict__ out)
{
    const int b = threadIdx.x;
    float loss = 0.0f;
    int j = TT - 1;
    for (int bi = 15; bi >= 0; --bi) {
        const size_t idx = ((size_t)(b * 16 + bi) << 10) + j;
        loss += seg[idx];
        j = exitc[idx];
    }
    atomicAdd(out, loss);
}

extern "C" void kernel_launch(void* const* d_in, const int* in_sizes, int n_in,
                              void* d_out, int out_size, void* d_ws, size_t ws_size,
                              hipStream_t stream)
{
    const float* preds   = (const float*)d_in[0];
    const float* targs   = (const float*)d_in[1];
    const float* subcoef = (const float*)d_in[2];
    float* out = (float*)d_out;

    const int B = in_sizes[0] / (TT * 4);

    const size_t dirsElems = (size_t)B * 16 * NW * 64;          // uint2 each
    const size_t dirsBytes = dirsElems * sizeof(uint2);         // ~17.8 MB @ B=64
    const size_t segBytes  = (size_t)B * 16 * 1024 * sizeof(float);   // 4 MB
    uint2* dirs = (uint2*)d_ws;
    float* seg  = (float*)((char*)d_ws + dirsBytes);
    unsigned short* exitc = (unsigned short*)((char*)d_ws + dirsBytes + segBytes);

    hipMemsetAsync(out, 0, sizeof(float), stream);
    dtw_forward<<<dim3(B), dim3(256), 0, stream>>>(preds, targs, dirs);
    dtw_bandwalk<<<dim3(B * 16), dim3(1024), 0, stream>>>(preds, targs, subcoef, dirs, seg, exitc);
    dtw_stitch<<<dim3(1), dim3(B), 0, stream>>>(seg, exitc, out);
}